// Round 2
// baseline (22657.448 us; speedup 1.0000x reference)
//
#include <hip/hip_runtime.h>
#include <hip/hip_bf16.h>

// LatticeLSTM on MI355X.
// Design: 8 sequences x 32 WGs (grid (8,32) x 256thr). Each WG owns 16 H-cols.
// Weights converted once per launch to bf16 and transposed into d_ws.
// Sequential T-loop with per-sequence FLAG-ARRAY barriers (2 per step):
// each WG stores its generation to flags[seq][wg] (no RMW serialization),
// wave 0 polls all 32 flags with ONE coalesced load + ballot.
// Shared state (h rows in d_out, pend ring) uses relaxed agent-scope (sc1)
// loads/stores; __syncthreads() before the flag store drains vmcnt so data
// stores are globally visible before the arrival flag.
//
// pmask is data-independent: m0=(t>=1), m1=(t>=3); c_plain only at t=0.
// grid.x = seq so one sequence's 32 WGs land on one XCD (round-robin dispatch).

#define Bq 8
#define Tq 1024
#define DCq 128
#define Hq 512
#define NWG 32
#define NTHR 256

// ws byte offsets (all 256B-aligned)
#define SYNC_OFF  0u           // flags[8][32] uint, 128B per seq
#define PEND_OFF  1024u        // 8*4*2*512*4 = 131072
#define WIHT_OFF  132096u      // bf16 [1536][128]
#define WHHT_OFF  525312u      // bf16 [1536][512]
#define AWIHT_OFF 2098176u     // bf16 [512][128]
#define AWHHT_OFF 2229248u     // bf16 [512][512]
#define WWIHT_OFF 2753536u     // bf16 [1536][128]
#define WWHHT_OFF 3146752u     // bf16 [1536][512]  (end 4719616)

__device__ __forceinline__ float bflo(unsigned u){ return __uint_as_float(u << 16); }
__device__ __forceinline__ float bfhi(unsigned u){ return __uint_as_float(u & 0xffff0000u); }
__device__ __forceinline__ float sigm(float x){ return 1.0f / (1.0f + __expf(-x)); }

__device__ __forceinline__ void fma4(float& acc, uint2 w, float4 v){
  acc = fmaf(bflo(w.x), v.x, acc);
  acc = fmaf(bfhi(w.x), v.y, acc);
  acc = fmaf(bflo(w.y), v.z, acc);
  acc = fmaf(bfhi(w.y), v.w, acc);
}

__device__ __forceinline__ float red16(float x){
  x += __shfl_xor(x, 8, 16);
  x += __shfl_xor(x, 4, 16);
  x += __shfl_xor(x, 2, 16);
  x += __shfl_xor(x, 1, 16);
  return x;
}

// coherent (agent-scope, sc1) load/store for cross-WG shared data
__device__ __forceinline__ float gload(const float* p){
  return __hip_atomic_load(p, __ATOMIC_RELAXED, __HIP_MEMORY_SCOPE_AGENT);
}
__device__ __forceinline__ void gstore(float* p, float v){
  __hip_atomic_store(p, v, __ATOMIC_RELAXED, __HIP_MEMORY_SCOPE_AGENT);
}

// Per-sequence flag-array barrier. flags = 32 uints (one 128B line per seq).
// Each WG stores its monotonic generation; wave 0 polls all 32 flags with a
// single 64-lane coalesced load (lanes 0-31 and 32-63 read the same words).
__device__ __forceinline__ void seq_barrier(unsigned* flags, int wg, unsigned target){
  __syncthreads();   // drains vmcnt -> prior sc1 data stores complete first
  if (threadIdx.x == 0){
    __hip_atomic_store(flags + wg, target, __ATOMIC_RELAXED, __HIP_MEMORY_SCOPE_AGENT);
  }
  if (threadIdx.x < 64){
    const int l = threadIdx.x & 31;
    for (;;){
      unsigned v = __hip_atomic_load(flags + l, __ATOMIC_RELAXED, __HIP_MEMORY_SCOPE_AGENT);
      if (__ballot(v >= target) == ~0ull) break;
      __builtin_amdgcn_s_sleep(1);
    }
  }
  __syncthreads();
}

// src [K][N] fp32 -> dst [N][K] bf16 (transpose + convert). K is pow2.
__global__ void transpose_bf16(const float* __restrict__ src, __hip_bfloat16* __restrict__ dst,
                               int kshift, int total, int N){
  const int K = 1 << kshift;
  for (int idx = blockIdx.x * blockDim.x + threadIdx.x; idx < total;
       idx += gridDim.x * blockDim.x){
    int n = idx >> kshift;
    int k = idx & (K - 1);
    dst[idx] = __float2bfloat16(src[(size_t)k * N + n]);
  }
}

__global__ void __launch_bounds__(NTHR)
lattice_main(const float* __restrict__ char_emb,
             const int*   __restrict__ word_ids,
             const float* __restrict__ sense_table,
             const float* __restrict__ bias_b,
             const float* __restrict__ bias_ab,
             const float* __restrict__ bias_wb,
             unsigned char* __restrict__ ws,
             float* __restrict__ out)
{
  const int seq  = blockIdx.x;   // x = seq: one seq's WGs share an XCD
  const int wg   = blockIdx.y;
  const int tid  = threadIdx.x;
  const int grp  = tid >> 4;
  const int lane = tid & 15;
  const int J    = wg * 16 + grp;     // owned H column

  unsigned* flags = (unsigned*)(ws + SYNC_OFF) + (size_t)seq * 32;  // 128B line per seq

  float* pend = (float*)(ws + PEND_OFF) + (size_t)seq * 4 * 2 * Hq; // [slot][k][col]

  const uint2* w_ihT  = (const uint2*)(ws + WIHT_OFF);
  const uint2* w_hhT  = (const uint2*)(ws + WHHT_OFF);
  const uint2* aw_ihT = (const uint2*)(ws + AWIHT_OFF);
  const uint2* aw_hhT = (const uint2*)(ws + AWHHT_OFF);
  const uint2* ww_ihT = (const uint2*)(ws + WWIHT_OFF);
  const uint2* ww_hhT = (const uint2*)(ws + WWHHT_OFF);

  // row pointers (512-col rows = 128 uint2, 128-col rows = 32 uint2)
  const uint2* whh_i = w_hhT  + (size_t)(0*Hq + J) * 128;
  const uint2* whh_o = w_hhT  + (size_t)(1*Hq + J) * 128;
  const uint2* whh_g = w_hhT  + (size_t)(2*Hq + J) * 128;
  const uint2* awhh  = aw_hhT + (size_t)J * 128;
  const uint2* wwh_f = ww_hhT + (size_t)(0*Hq + J) * 128;
  const uint2* wwh_i = ww_hhT + (size_t)(1*Hq + J) * 128;
  const uint2* wwh_g = ww_hhT + (size_t)(2*Hq + J) * 128;
  const uint2* wih_i = w_ihT  + (size_t)(0*Hq + J) * 32;
  const uint2* wih_o = w_ihT  + (size_t)(1*Hq + J) * 32;
  const uint2* wih_g = w_ihT  + (size_t)(2*Hq + J) * 32;
  const uint2* awih  = aw_ihT + (size_t)J * 32;
  const uint2* wwi_f = ww_ihT + (size_t)(0*Hq + J) * 32;
  const uint2* wwi_i = ww_ihT + (size_t)(1*Hq + J) * 32;
  const uint2* wwi_g = ww_ihT + (size_t)(2*Hq + J) * 32;

  const float b_i  = bias_b[J], b_o = bias_b[Hq + J], b_g = bias_b[2*Hq + J];
  const float ab_J = bias_ab[J];
  const float wb_f = bias_wb[J], wb_i = bias_wb[Hq + J], wb_g = bias_wb[2*Hq + J];

  float* out_h = out + (size_t)seq * Tq * Hq;            // hs block
  float* out_c = out + ((size_t)Bq + seq) * Tq * Hq;     // cs block

  __shared__ __align__(16) float sh_h[Hq];
  __shared__ __align__(16) float sh_p0[Hq];
  __shared__ __align__(16) float sh_p1[Hq];
  __shared__ __align__(16) float sh_x[DCq];
  __shared__ __align__(16) float sh_xw0[DCq];
  __shared__ __align__(16) float sh_xw1[DCq];

  unsigned bgen = 0;

  for (int t = 0; t < Tq; ++t){
    const int r = t & 3;
    // ---- stage phase A inputs ----
    {
      const float* hsrc = out_h + (size_t)(t - 1) * Hq;
      const float* p0 = pend + (r * 2 + 0) * Hq;
      const float* p1 = pend + (r * 2 + 1) * Hq;
      for (int i = tid; i < Hq; i += NTHR){
        sh_h[i]  = (t == 0) ? 0.0f : gload(hsrc + i);
        sh_p0[i] = gload(p0 + i);
        sh_p1[i] = gload(p1 + i);
      }
      if (tid < DCq) sh_x[tid] = char_emb[((size_t)seq * Tq + t) * DCq + tid];
    }
    __syncthreads();

    // ---- char-cell dots: i,o,g over h (K=512) + alpha over pend + input parts ----
    float a_i = 0.f, a_o = 0.f, a_g = 0.f, a_p0 = 0.f, a_p1 = 0.f, a_xa = 0.f;
    for (int it = 0; it < 8; ++it){
      const int k0 = it * 64 + lane * 4;   // 4 consecutive k per lane: 2-way LDS aliasing (free)
      const int q  = k0 >> 2;
      float4 hv  = *(const float4*)(sh_h  + k0);
      float4 p0v = *(const float4*)(sh_p0 + k0);
      float4 p1v = *(const float4*)(sh_p1 + k0);
      fma4(a_i, whh_i[q], hv);
      fma4(a_o, whh_o[q], hv);
      fma4(a_g, whh_g[q], hv);
      uint2 aw = awhh[q];
      fma4(a_p0, aw, p0v);
      fma4(a_p1, aw, p1v);
    }
    for (int it = 0; it < 2; ++it){
      const int k0 = it * 64 + lane * 4;
      const int q  = k0 >> 2;
      float4 xv = *(const float4*)(sh_x + k0);
      fma4(a_i,  wih_i[q], xv);
      fma4(a_o,  wih_o[q], xv);
      fma4(a_g,  wih_g[q], xv);
      fma4(a_xa, awih[q],  xv);
    }
    a_i  = red16(a_i);  a_o  = red16(a_o);  a_g  = red16(a_g);
    a_p0 = red16(a_p0); a_p1 = red16(a_p1); a_xa = red16(a_xa);

    const float gi = sigm(a_i + b_i);
    const float go = sigm(a_o + b_o);
    const float gg = tanhf(a_g + b_g);
    float c1;
    if (t == 0){
      c1 = gi * gg;                       // c_plain with c=0
    } else {
      const float base = a_xa + ab_J;
      const float ea0 = __expf(sigm(base + a_p0));   // m0 = 1 for t>=1
      const float ei  = __expf(gi);
      float num = ei * gg + ea0 * sh_p0[J];
      float den = ei + ea0;
      if (t >= 3){                                    // m1 = 1 for t>=3
        const float ea1 = __expf(sigm(base + a_p1));
        num += ea1 * sh_p1[J];
        den += ea1;
      }
      c1 = num / den;
    }
    const float h1 = go * tanhf(c1);
    if (lane == 0){
      gstore(out_h + (size_t)t * Hq + J, h1);   // read by peers: coherent store
      out_c[(size_t)t * Hq + J] = c1;           // only harness reads: plain store
    }
    ++bgen;
    seq_barrier(flags, wg, bgen);

    // ---- word-cell: wg = xw@ww_ih + h1@ww_hh + wb ----
    {
      const float* h1src = out_h + (size_t)t * Hq;
      for (int i = tid; i < Hq; i += NTHR) sh_h[i] = gload(h1src + i);
      if (tid < DCq){
        const int w0 = word_ids[((size_t)seq * Tq + t) * 2 + 0];
        sh_xw0[tid] = sense_table[(size_t)w0 * DCq + tid];
      } else {
        const int w1 = word_ids[((size_t)seq * Tq + t) * 2 + 1];
        sh_xw1[tid - DCq] = sense_table[(size_t)w1 * DCq + (tid - DCq)];
      }
    }
    __syncthreads();

    float r_f = 0.f, r_i = 0.f, r_g = 0.f;
    float x_f0 = 0.f, x_i0 = 0.f, x_g0 = 0.f, x_f1 = 0.f, x_i1 = 0.f, x_g1 = 0.f;
    for (int it = 0; it < 8; ++it){
      const int k0 = it * 64 + lane * 4;
      const int q  = k0 >> 2;
      float4 hv = *(const float4*)(sh_h + k0);
      fma4(r_f, wwh_f[q], hv);
      fma4(r_i, wwh_i[q], hv);
      fma4(r_g, wwh_g[q], hv);
    }
    for (int it = 0; it < 2; ++it){
      const int k0 = it * 64 + lane * 4;
      const int q  = k0 >> 2;
      float4 x0 = *(const float4*)(sh_xw0 + k0);
      float4 x1 = *(const float4*)(sh_xw1 + k0);
      uint2 wf = wwi_f[q], wi = wwi_i[q], wgq = wwi_g[q];
      fma4(x_f0, wf, x0);  fma4(x_f1, wf, x1);
      fma4(x_i0, wi, x0);  fma4(x_i1, wi, x1);
      fma4(x_g0, wgq, x0); fma4(x_g1, wgq, x1);
    }
    r_f  = red16(r_f);  r_i  = red16(r_i);  r_g  = red16(r_g);
    x_f0 = red16(x_f0); x_i0 = red16(x_i0); x_g0 = red16(x_g0);
    x_f1 = red16(x_f1); x_i1 = red16(x_i1); x_g1 = red16(x_g1);

    if (lane == 0){
      const float f0  = sigm(r_f + x_f0 + wb_f);
      const float i0  = sigm(r_i + x_i0 + wb_i);
      const float g0  = tanhf(r_g + x_g0 + wb_g);
      const float cw0 = f0 * c1 + i0 * g0;
      const float f1  = sigm(r_f + x_f1 + wb_f);
      const float i1  = sigm(r_i + x_i1 + wb_i);
      const float g1  = tanhf(r_g + x_g1 + wb_g);
      const float cw1 = f1 * c1 + i1 * g1;
      // unconditional ring writes; invalid (t near T) slots are never read
      gstore(pend + (((t + 1) & 3) * 2 + 0) * Hq + J, cw0);
      gstore(pend + (((t + 3) & 3) * 2 + 1) * Hq + J, cw1);
    }
    ++bgen;
    seq_barrier(flags, wg, bgen);
  }
}

extern "C" void kernel_launch(void* const* d_in, const int* in_sizes, int n_in,
                              void* d_out, int out_size, void* d_ws, size_t ws_size,
                              hipStream_t stream){
  const float* char_emb = (const float*)d_in[0];
  const int*   word_ids = (const int*)d_in[1];
  const float* sense    = (const float*)d_in[2];
  const float* w_ih     = (const float*)d_in[3];
  const float* w_hh     = (const float*)d_in[4];
  const float* bb       = (const float*)d_in[5];
  const float* aw_ih    = (const float*)d_in[6];
  const float* aw_hh    = (const float*)d_in[7];
  const float* ab       = (const float*)d_in[8];
  const float* ww_ih    = (const float*)d_in[9];
  const float* ww_hh    = (const float*)d_in[10];
  const float* wb       = (const float*)d_in[11];
  unsigned char* ws = (unsigned char*)d_ws;
  float* out = (float*)d_out;

  // zero sync flags + pend ring (ws is re-poisoned before every launch)
  hipMemsetAsync(ws, 0, WIHT_OFF, stream);

  // one-time (per launch) weight convert+transpose to bf16
  transpose_bf16<<<512, NTHR, 0, stream>>>(w_ih,  (__hip_bfloat16*)(ws + WIHT_OFF),  7, 128*1536, 1536);
  transpose_bf16<<<512, NTHR, 0, stream>>>(w_hh,  (__hip_bfloat16*)(ws + WHHT_OFF),  9, 512*1536, 1536);
  transpose_bf16<<<512, NTHR, 0, stream>>>(aw_ih, (__hip_bfloat16*)(ws + AWIHT_OFF), 7, 128*512,  512);
  transpose_bf16<<<512, NTHR, 0, stream>>>(aw_hh, (__hip_bfloat16*)(ws + AWHHT_OFF), 9, 512*512,  512);
  transpose_bf16<<<512, NTHR, 0, stream>>>(ww_ih, (__hip_bfloat16*)(ws + WWIHT_OFF), 7, 128*1536, 1536);
  transpose_bf16<<<512, NTHR, 0, stream>>>(ww_hh, (__hip_bfloat16*)(ws + WWHHT_OFF), 9, 512*1536, 1536);

  dim3 grid(Bq, NWG);   // x = seq (XCD-local), y = wg slice; 256 WGs co-resident
  lattice_main<<<grid, NTHR, 0, stream>>>(char_emb, word_ids, sense, bb, ab, wb, ws, out);
}

// Round 3
// 8896.346 us; speedup vs baseline: 2.5468x; 2.5468x over previous
//
#include <hip/hip_runtime.h>
#include <hip/hip_bf16.h>

// LatticeLSTM on MI355X — Round 3.
// Key changes vs R2:
//  (A) Weights live in REGISTERS: each lane's weight addresses are invariant
//      across t (fixed column J, fixed k-chunk), total 4.6 MB bf16 / 64K lanes
//      = 140 VGPR/lane. Loaded once before the t-loop; K-loop is pure FMA on
//      LDS-broadcast activations. Eliminates 143 KB/CU/step weight streaming.
//      __launch_bounds__(256,1): 1 wave/SIMD is fine (need only 1 WG/CU).
//  (B) Flag-array barrier with LOW-RATE polling: check first, then s_sleep(4)
//      (256 cyc) backoff. R2's s_sleep(1) 64-lane poll storm (18.6 GB FETCH)
//      starved the arrival stores at the TCC.
//
// pmask is data-independent: m0=(t>=1), m1=(t>=3); c_plain only at t=0.
// grid (seq, wg): one sequence's 32 WGs land on one XCD (round-robin heuristic,
// perf-only). Cross-WG state via relaxed agent-scope (sc1) ops; the
// __syncthreads() before the flag store drains vmcnt so data stores are
// globally visible before the arrival flag.

#define Bq 8
#define Tq 1024
#define DCq 128
#define Hq 512
#define NWG 32
#define NTHR 256

// ws byte offsets (all 256B-aligned)
#define SYNC_OFF  0u           // flags[8][32] uint, 128B per seq
#define PEND_OFF  1024u        // 8*4*2*512*4 = 131072
#define WIHT_OFF  132096u      // bf16 [1536][128]
#define WHHT_OFF  525312u      // bf16 [1536][512]
#define AWIHT_OFF 2098176u     // bf16 [512][128]
#define AWHHT_OFF 2229248u     // bf16 [512][512]
#define WWIHT_OFF 2753536u     // bf16 [1536][128]
#define WWHHT_OFF 3146752u     // bf16 [1536][512]  (end 4719616)

__device__ __forceinline__ float bflo(unsigned u){ return __uint_as_float(u << 16); }
__device__ __forceinline__ float bfhi(unsigned u){ return __uint_as_float(u & 0xffff0000u); }
__device__ __forceinline__ float sigm(float x){ return 1.0f / (1.0f + __expf(-x)); }

__device__ __forceinline__ void fma4(float& acc, uint2 w, float4 v){
  acc = fmaf(bflo(w.x), v.x, acc);
  acc = fmaf(bfhi(w.x), v.y, acc);
  acc = fmaf(bflo(w.y), v.z, acc);
  acc = fmaf(bfhi(w.y), v.w, acc);
}

__device__ __forceinline__ float red16(float x){
  x += __shfl_xor(x, 8, 16);
  x += __shfl_xor(x, 4, 16);
  x += __shfl_xor(x, 2, 16);
  x += __shfl_xor(x, 1, 16);
  return x;
}

// coherent (agent-scope, sc1) load/store for cross-WG shared data
__device__ __forceinline__ float gload(const float* p){
  return __hip_atomic_load(p, __ATOMIC_RELAXED, __HIP_MEMORY_SCOPE_AGENT);
}
__device__ __forceinline__ void gstore(float* p, float v){
  __hip_atomic_store(p, v, __ATOMIC_RELAXED, __HIP_MEMORY_SCOPE_AGENT);
}

// Per-sequence flag-array barrier, low-rate polling.
__device__ __forceinline__ void seq_barrier(unsigned* flags, int wg, unsigned target){
  __syncthreads();   // drains vmcnt -> prior sc1 data stores complete first
  if (threadIdx.x == 0){
    __hip_atomic_store(flags + wg, target, __ATOMIC_RELAXED, __HIP_MEMORY_SCOPE_AGENT);
  }
  if (threadIdx.x < 64){
    const int l = threadIdx.x & 31;
    unsigned v = __hip_atomic_load(flags + l, __ATOMIC_RELAXED, __HIP_MEMORY_SCOPE_AGENT);
    while (__ballot(v >= target) != ~0ull){
      __builtin_amdgcn_s_sleep(4);   // 256-cyc backoff: keep TCC quiet for arrivers
      v = __hip_atomic_load(flags + l, __ATOMIC_RELAXED, __HIP_MEMORY_SCOPE_AGENT);
    }
  }
  __syncthreads();
}

// src [K][N] fp32 -> dst [N][K] bf16 (transpose + convert). K is pow2.
__global__ void transpose_bf16(const float* __restrict__ src, __hip_bfloat16* __restrict__ dst,
                               int kshift, int total, int N){
  const int K = 1 << kshift;
  for (int idx = blockIdx.x * blockDim.x + threadIdx.x; idx < total;
       idx += gridDim.x * blockDim.x){
    int n = idx >> kshift;
    int k = idx & (K - 1);
    dst[idx] = __float2bfloat16(src[(size_t)k * N + n]);
  }
}

__global__ void __launch_bounds__(NTHR, 1)
lattice_main(const float* __restrict__ char_emb,
             const int*   __restrict__ word_ids,
             const float* __restrict__ sense_table,
             const float* __restrict__ bias_b,
             const float* __restrict__ bias_ab,
             const float* __restrict__ bias_wb,
             unsigned char* __restrict__ ws,
             float* __restrict__ out)
{
  const int seq  = blockIdx.x;   // x = seq: one seq's WGs share an XCD (perf heuristic)
  const int wg   = blockIdx.y;
  const int tid  = threadIdx.x;
  const int grp  = tid >> 4;
  const int lane = tid & 15;
  const int J    = wg * 16 + grp;     // owned H column

  unsigned* flags = (unsigned*)(ws + SYNC_OFF) + (size_t)seq * 32;  // 128B line per seq
  float* pend = (float*)(ws + PEND_OFF) + (size_t)seq * 4 * 2 * Hq; // [slot][k][col]

  const uint2* w_ihT  = (const uint2*)(ws + WIHT_OFF);
  const uint2* w_hhT  = (const uint2*)(ws + WHHT_OFF);
  const uint2* aw_ihT = (const uint2*)(ws + AWIHT_OFF);
  const uint2* aw_hhT = (const uint2*)(ws + AWHHT_OFF);
  const uint2* ww_ihT = (const uint2*)(ws + WWIHT_OFF);
  const uint2* ww_hhT = (const uint2*)(ws + WWHHT_OFF);

  // ---- hoist ALL weights into registers (addresses are t-invariant) ----
  // char phase: 8 iters * 4 uint2 = 64 VGPR; ih: 2 iters * 4 uint2 = 16 VGPR
  // word phase: 8 iters * 3 uint2 = 48 VGPR; ih: 2 iters * 3 uint2 = 12 VGPR
  uint2 Rwhh_i[8], Rwhh_o[8], Rwhh_g[8], Rawhh[8];
  uint2 Rwwh_f[8], Rwwh_i[8], Rwwh_g[8];
  uint2 Rwih_i[2], Rwih_o[2], Rwih_g[2], Rawih[2];
  uint2 Rwwi_f[2], Rwwi_i[2], Rwwi_g[2];
  {
    const uint2* whh_i = w_hhT  + (size_t)(0*Hq + J) * 128;
    const uint2* whh_o = w_hhT  + (size_t)(1*Hq + J) * 128;
    const uint2* whh_g = w_hhT  + (size_t)(2*Hq + J) * 128;
    const uint2* awhh  = aw_hhT + (size_t)J * 128;
    const uint2* wwh_f = ww_hhT + (size_t)(0*Hq + J) * 128;
    const uint2* wwh_i = ww_hhT + (size_t)(1*Hq + J) * 128;
    const uint2* wwh_g = ww_hhT + (size_t)(2*Hq + J) * 128;
#pragma unroll
    for (int it = 0; it < 8; ++it){
      const int q = it * 16 + lane;
      Rwhh_i[it] = whh_i[q];  Rwhh_o[it] = whh_o[q];  Rwhh_g[it] = whh_g[q];
      Rawhh[it]  = awhh[q];
      Rwwh_f[it] = wwh_f[q];  Rwwh_i[it] = wwh_i[q];  Rwwh_g[it] = wwh_g[q];
    }
    const uint2* wih_i = w_ihT  + (size_t)(0*Hq + J) * 32;
    const uint2* wih_o = w_ihT  + (size_t)(1*Hq + J) * 32;
    const uint2* wih_g = w_ihT  + (size_t)(2*Hq + J) * 32;
    const uint2* awih  = aw_ihT + (size_t)J * 32;
    const uint2* wwi_f = ww_ihT + (size_t)(0*Hq + J) * 32;
    const uint2* wwi_i = ww_ihT + (size_t)(1*Hq + J) * 32;
    const uint2* wwi_g = ww_ihT + (size_t)(2*Hq + J) * 32;
#pragma unroll
    for (int it = 0; it < 2; ++it){
      const int q = it * 16 + lane;
      Rwih_i[it] = wih_i[q];  Rwih_o[it] = wih_o[q];  Rwih_g[it] = wih_g[q];
      Rawih[it]  = awih[q];
      Rwwi_f[it] = wwi_f[q];  Rwwi_i[it] = wwi_i[q];  Rwwi_g[it] = wwi_g[q];
    }
  }

  const float b_i  = bias_b[J], b_o = bias_b[Hq + J], b_g = bias_b[2*Hq + J];
  const float ab_J = bias_ab[J];
  const float wb_f = bias_wb[J], wb_i = bias_wb[Hq + J], wb_g = bias_wb[2*Hq + J];

  float* out_h = out + (size_t)seq * Tq * Hq;            // hs block
  float* out_c = out + ((size_t)Bq + seq) * Tq * Hq;     // cs block

  __shared__ __align__(16) float sh_h[Hq];
  __shared__ __align__(16) float sh_p0[Hq];
  __shared__ __align__(16) float sh_p1[Hq];
  __shared__ __align__(16) float sh_x[DCq];
  __shared__ __align__(16) float sh_xw0[DCq];
  __shared__ __align__(16) float sh_xw1[DCq];

  unsigned bgen = 0;

  for (int t = 0; t < Tq; ++t){
    const int r = t & 3;
    // ---- stage phase A inputs (sc1 loads; both loop iters issue together) ----
    {
      const float* hsrc = out_h + (size_t)(t - 1) * Hq;
      const float* p0 = pend + (r * 2 + 0) * Hq;
      const float* p1 = pend + (r * 2 + 1) * Hq;
#pragma unroll
      for (int u = 0; u < 2; ++u){
        const int i = tid + u * NTHR;
        sh_h[i]  = (t == 0) ? 0.0f : gload(hsrc + i);
        sh_p0[i] = gload(p0 + i);
        sh_p1[i] = gload(p1 + i);
      }
      if (tid < DCq) sh_x[tid] = char_emb[((size_t)seq * Tq + t) * DCq + tid];
    }
    __syncthreads();

    // ---- char-cell dots: i,o,g over h (K=512) + alpha over pend + input parts ----
    float a_i = 0.f, a_o = 0.f, a_g = 0.f, a_p0 = 0.f, a_p1 = 0.f, a_xa = 0.f;
#pragma unroll
    for (int it = 0; it < 8; ++it){
      const int k0 = it * 64 + lane * 4;   // 2-way LDS aliasing (free)
      float4 hv  = *(const float4*)(sh_h  + k0);
      float4 p0v = *(const float4*)(sh_p0 + k0);
      float4 p1v = *(const float4*)(sh_p1 + k0);
      fma4(a_i, Rwhh_i[it], hv);
      fma4(a_o, Rwhh_o[it], hv);
      fma4(a_g, Rwhh_g[it], hv);
      fma4(a_p0, Rawhh[it], p0v);
      fma4(a_p1, Rawhh[it], p1v);
    }
#pragma unroll
    for (int it = 0; it < 2; ++it){
      const int k0 = it * 64 + lane * 4;
      float4 xv = *(const float4*)(sh_x + k0);
      fma4(a_i,  Rwih_i[it], xv);
      fma4(a_o,  Rwih_o[it], xv);
      fma4(a_g,  Rwih_g[it], xv);
      fma4(a_xa, Rawih[it],  xv);
    }
    a_i  = red16(a_i);  a_o  = red16(a_o);  a_g  = red16(a_g);
    a_p0 = red16(a_p0); a_p1 = red16(a_p1); a_xa = red16(a_xa);

    const float gi = sigm(a_i + b_i);
    const float go = sigm(a_o + b_o);
    const float gg = tanhf(a_g + b_g);
    float c1;
    if (t == 0){
      c1 = gi * gg;                       // c_plain with c=0
    } else {
      const float base = a_xa + ab_J;
      const float ea0 = __expf(sigm(base + a_p0));   // m0 = 1 for t>=1
      const float ei  = __expf(gi);
      float num = ei * gg + ea0 * sh_p0[J];
      float den = ei + ea0;
      if (t >= 3){                                    // m1 = 1 for t>=3
        const float ea1 = __expf(sigm(base + a_p1));
        num += ea1 * sh_p1[J];
        den += ea1;
      }
      c1 = num / den;
    }
    const float h1 = go * tanhf(c1);
    if (lane == 0){
      gstore(out_h + (size_t)t * Hq + J, h1);   // read by peers: coherent store
      out_c[(size_t)t * Hq + J] = c1;           // only harness reads: plain store
    }
    ++bgen;
    seq_barrier(flags, wg, bgen);

    // ---- word-cell: wg = xw@ww_ih + h1@ww_hh + wb ----
    {
      const float* h1src = out_h + (size_t)t * Hq;
#pragma unroll
      for (int u = 0; u < 2; ++u){
        const int i = tid + u * NTHR;
        sh_h[i] = gload(h1src + i);
      }
      if (tid < DCq){
        const int w0 = word_ids[((size_t)seq * Tq + t) * 2 + 0];
        sh_xw0[tid] = sense_table[(size_t)w0 * DCq + tid];
      } else {
        const int w1 = word_ids[((size_t)seq * Tq + t) * 2 + 1];
        sh_xw1[tid - DCq] = sense_table[(size_t)w1 * DCq + (tid - DCq)];
      }
    }
    __syncthreads();

    float r_f = 0.f, r_i = 0.f, r_g = 0.f;
    float x_f0 = 0.f, x_i0 = 0.f, x_g0 = 0.f, x_f1 = 0.f, x_i1 = 0.f, x_g1 = 0.f;
#pragma unroll
    for (int it = 0; it < 8; ++it){
      const int k0 = it * 64 + lane * 4;
      float4 hv = *(const float4*)(sh_h + k0);
      fma4(r_f, Rwwh_f[it], hv);
      fma4(r_i, Rwwh_i[it], hv);
      fma4(r_g, Rwwh_g[it], hv);
    }
#pragma unroll
    for (int it = 0; it < 2; ++it){
      const int k0 = it * 64 + lane * 4;
      float4 x0 = *(const float4*)(sh_xw0 + k0);
      float4 x1 = *(const float4*)(sh_xw1 + k0);
      fma4(x_f0, Rwwi_f[it], x0);  fma4(x_f1, Rwwi_f[it], x1);
      fma4(x_i0, Rwwi_i[it], x0);  fma4(x_i1, Rwwi_i[it], x1);
      fma4(x_g0, Rwwi_g[it], x0);  fma4(x_g1, Rwwi_g[it], x1);
    }
    r_f  = red16(r_f);  r_i  = red16(r_i);  r_g  = red16(r_g);
    x_f0 = red16(x_f0); x_i0 = red16(x_i0); x_g0 = red16(x_g0);
    x_f1 = red16(x_f1); x_i1 = red16(x_i1); x_g1 = red16(x_g1);

    if (lane == 0){
      const float f0  = sigm(r_f + x_f0 + wb_f);
      const float i0  = sigm(r_i + x_i0 + wb_i);
      const float g0  = tanhf(r_g + x_g0 + wb_g);
      const float cw0 = f0 * c1 + i0 * g0;
      const float f1  = sigm(r_f + x_f1 + wb_f);
      const float i1  = sigm(r_i + x_i1 + wb_i);
      const float g1  = tanhf(r_g + x_g1 + wb_g);
      const float cw1 = f1 * c1 + i1 * g1;
      // unconditional ring writes; invalid (t near T) slots are never read
      gstore(pend + (((t + 1) & 3) * 2 + 0) * Hq + J, cw0);
      gstore(pend + (((t + 3) & 3) * 2 + 1) * Hq + J, cw1);
    }
    ++bgen;
    seq_barrier(flags, wg, bgen);
  }
}

extern "C" void kernel_launch(void* const* d_in, const int* in_sizes, int n_in,
                              void* d_out, int out_size, void* d_ws, size_t ws_size,
                              hipStream_t stream){
  const float* char_emb = (const float*)d_in[0];
  const int*   word_ids = (const int*)d_in[1];
  const float* sense    = (const float*)d_in[2];
  const float* w_ih     = (const float*)d_in[3];
  const float* w_hh     = (const float*)d_in[4];
  const float* bb       = (const float*)d_in[5];
  const float* aw_ih    = (const float*)d_in[6];
  const float* aw_hh    = (const float*)d_in[7];
  const float* ab       = (const float*)d_in[8];
  const float* ww_ih    = (const float*)d_in[9];
  const float* ww_hh    = (const float*)d_in[10];
  const float* wb       = (const float*)d_in[11];
  unsigned char* ws = (unsigned char*)d_ws;
  float* out = (float*)d_out;

  // zero sync flags + pend ring (ws is re-poisoned before every launch)
  hipMemsetAsync(ws, 0, WIHT_OFF, stream);

  // one-time (per launch) weight convert+transpose to bf16
  transpose_bf16<<<512, NTHR, 0, stream>>>(w_ih,  (__hip_bfloat16*)(ws + WIHT_OFF),  7, 128*1536, 1536);
  transpose_bf16<<<512, NTHR, 0, stream>>>(w_hh,  (__hip_bfloat16*)(ws + WHHT_OFF),  9, 512*1536, 1536);
  transpose_bf16<<<512, NTHR, 0, stream>>>(aw_ih, (__hip_bfloat16*)(ws + AWIHT_OFF), 7, 128*512,  512);
  transpose_bf16<<<512, NTHR, 0, stream>>>(aw_hh, (__hip_bfloat16*)(ws + AWHHT_OFF), 9, 512*512,  512);
  transpose_bf16<<<512, NTHR, 0, stream>>>(ww_ih, (__hip_bfloat16*)(ws + WWIHT_OFF), 7, 128*1536, 1536);
  transpose_bf16<<<512, NTHR, 0, stream>>>(ww_hh, (__hip_bfloat16*)(ws + WWHHT_OFF), 9, 512*1536, 1536);

  dim3 grid(Bq, NWG);   // x = seq (XCD-local heuristic), y = wg slice; 256 WGs co-resident
  lattice_main<<<grid, NTHR, 0, stream>>>(char_emb, word_ids, sense, bb, ab, wb, ws, out);
}

// Round 4
// 7319.588 us; speedup vs baseline: 3.0955x; 1.2154x over previous
//
#include <hip/hip_runtime.h>
#include <hip/hip_bf16.h>

// LatticeLSTM on MI355X — Round 4: barrier-free {value,generation} dataflow.
//  - Every cross-WG datum is published as ONE aligned 8-byte word:
//    low 32 = fp32 value, high 32 = generation (= production step + 1).
//    Atomicity of the 8B store orders gen with value -> no flags, no WG-wide
//    vmcnt drain, no release fences, no barrier round trips.
//  - Consumers spin per-thread on exactly the 2 columns they stage (distinct
//    addresses; no hot-line contention). Poll targets:
//      p0 (cw0, slot t&3,k0): gen >= t      (valid t>=1)
//      p1 (cw1, slot t&3,k1): gen >= t-2    (valid t>=3)
//      h1 (parity t&1)      : gen >= t+1
//  - Phase B stages h1 into persistent LDS; phase A of t+1 reuses it (no
//    re-poll of h). Weights stay hoisted in registers (R3).
//  - Progress requires all 256 WGs co-resident (1 WG/CU; LDS 7.5KB, VGPR<256).
// pmask is data-independent: m0=(t>=1), m1=(t>=3); c_plain only at t=0.

#define Bq 8
#define Tq 1024
#define DCq 128
#define Hq 512
#define NWG 32
#define NTHR 256

typedef unsigned long long u64;

// ws byte offsets
#define HPUB_OFF  0u         // u64 h_pub[8][2][512]     = 65536
#define PENDP_OFF 65536u     // u64 pend[8][4][2][512]   = 262144
#define WIHT_OFF  327680u    // bf16 [1536][128]
#define WHHT_OFF  720896u    // bf16 [1536][512]
#define AWIHT_OFF 2293760u   // bf16 [512][128]
#define AWHHT_OFF 2424832u   // bf16 [512][512]
#define WWIHT_OFF 2949120u   // bf16 [1536][128]
#define WWHHT_OFF 3342336u   // bf16 [1536][512]  (end 4915200)

__device__ __forceinline__ float bflo(unsigned u){ return __uint_as_float(u << 16); }
__device__ __forceinline__ float bfhi(unsigned u){ return __uint_as_float(u & 0xffff0000u); }
__device__ __forceinline__ float sigm(float x){ return 1.0f / (1.0f + __expf(-x)); }

__device__ __forceinline__ void fma4(float& acc, uint2 w, float4 v){
  acc = fmaf(bflo(w.x), v.x, acc);
  acc = fmaf(bfhi(w.x), v.y, acc);
  acc = fmaf(bflo(w.y), v.z, acc);
  acc = fmaf(bfhi(w.y), v.w, acc);
}

__device__ __forceinline__ float red16(float x){
  x += __shfl_xor(x, 8, 16);
  x += __shfl_xor(x, 4, 16);
  x += __shfl_xor(x, 2, 16);
  x += __shfl_xor(x, 1, 16);
  return x;
}

__device__ __forceinline__ u64 pack64(float v, unsigned gen){
  return ((u64)gen << 32) | (u64)__float_as_uint(v);
}
__device__ __forceinline__ void pub64(u64* p, float v, unsigned gen){
  __hip_atomic_store(p, pack64(v, gen), __ATOMIC_RELAXED, __HIP_MEMORY_SCOPE_AGENT);
}
// spin until gen(word) >= tgt, return value. Addresses are per-thread unique.
__device__ __forceinline__ float spin64(const u64* p, unsigned tgt){
  u64 v = __hip_atomic_load(p, __ATOMIC_RELAXED, __HIP_MEMORY_SCOPE_AGENT);
  while ((unsigned)(v >> 32) < tgt){
    __builtin_amdgcn_s_sleep(1);
    v = __hip_atomic_load(p, __ATOMIC_RELAXED, __HIP_MEMORY_SCOPE_AGENT);
  }
  return __uint_as_float((unsigned)v);
}

// src [K][N] fp32 -> dst [N][K] bf16 (transpose + convert). K is pow2.
__global__ void transpose_bf16(const float* __restrict__ src, __hip_bfloat16* __restrict__ dst,
                               int kshift, int total, int N){
  const int K = 1 << kshift;
  for (int idx = blockIdx.x * blockDim.x + threadIdx.x; idx < total;
       idx += gridDim.x * blockDim.x){
    int n = idx >> kshift;
    int k = idx & (K - 1);
    dst[idx] = __float2bfloat16(src[(size_t)k * N + n]);
  }
}

__global__ void __launch_bounds__(NTHR, 1)
lattice_main(const float* __restrict__ char_emb,
             const int*   __restrict__ word_ids,
             const float* __restrict__ sense_table,
             const float* __restrict__ bias_b,
             const float* __restrict__ bias_ab,
             const float* __restrict__ bias_wb,
             unsigned char* __restrict__ ws,
             float* __restrict__ out)
{
  const int seq  = blockIdx.x;   // x = seq: one seq's WGs share an XCD (perf heuristic)
  const int wg   = blockIdx.y;
  const int tid  = threadIdx.x;
  const int grp  = tid >> 4;
  const int lane = tid & 15;
  const int J    = wg * 16 + grp;     // owned H column
  const int i0   = tid * 2, i1 = tid * 2 + 1;   // poll columns for this thread

  u64* hpub = (u64*)(ws + HPUB_OFF)  + (size_t)seq * 2 * Hq;      // [parity][col]
  u64* pnd  = (u64*)(ws + PENDP_OFF) + (size_t)seq * 4 * 2 * Hq;  // [slot][k][col]

  const uint2* w_ihT  = (const uint2*)(ws + WIHT_OFF);
  const uint2* w_hhT  = (const uint2*)(ws + WHHT_OFF);
  const uint2* aw_ihT = (const uint2*)(ws + AWIHT_OFF);
  const uint2* aw_hhT = (const uint2*)(ws + AWHHT_OFF);
  const uint2* ww_ihT = (const uint2*)(ws + WWIHT_OFF);
  const uint2* ww_hhT = (const uint2*)(ws + WWHHT_OFF);

  // ---- hoist ALL weights into registers (addresses are t-invariant) ----
  uint2 Rwhh_i[8], Rwhh_o[8], Rwhh_g[8], Rawhh[8];
  uint2 Rwwh_f[8], Rwwh_i[8], Rwwh_g[8];
  uint2 Rwih_i[2], Rwih_o[2], Rwih_g[2], Rawih[2];
  uint2 Rwwi_f[2], Rwwi_i[2], Rwwi_g[2];
  {
    const uint2* whh_i = w_hhT  + (size_t)(0*Hq + J) * 128;
    const uint2* whh_o = w_hhT  + (size_t)(1*Hq + J) * 128;
    const uint2* whh_g = w_hhT  + (size_t)(2*Hq + J) * 128;
    const uint2* awhh  = aw_hhT + (size_t)J * 128;
    const uint2* wwh_f = ww_hhT + (size_t)(0*Hq + J) * 128;
    const uint2* wwh_i = ww_hhT + (size_t)(1*Hq + J) * 128;
    const uint2* wwh_g = ww_hhT + (size_t)(2*Hq + J) * 128;
#pragma unroll
    for (int it = 0; it < 8; ++it){
      const int q = it * 16 + lane;
      Rwhh_i[it] = whh_i[q];  Rwhh_o[it] = whh_o[q];  Rwhh_g[it] = whh_g[q];
      Rawhh[it]  = awhh[q];
      Rwwh_f[it] = wwh_f[q];  Rwwh_i[it] = wwh_i[q];  Rwwh_g[it] = wwh_g[q];
    }
    const uint2* wih_i = w_ihT  + (size_t)(0*Hq + J) * 32;
    const uint2* wih_o = w_ihT  + (size_t)(1*Hq + J) * 32;
    const uint2* wih_g = w_ihT  + (size_t)(2*Hq + J) * 32;
    const uint2* awih  = aw_ihT + (size_t)J * 32;
    const uint2* wwi_f = ww_ihT + (size_t)(0*Hq + J) * 32;
    const uint2* wwi_i = ww_ihT + (size_t)(1*Hq + J) * 32;
    const uint2* wwi_g = ww_ihT + (size_t)(2*Hq + J) * 32;
#pragma unroll
    for (int it = 0; it < 2; ++it){
      const int q = it * 16 + lane;
      Rwih_i[it] = wih_i[q];  Rwih_o[it] = wih_o[q];  Rwih_g[it] = wih_g[q];
      Rawih[it]  = awih[q];
      Rwwi_f[it] = wwi_f[q];  Rwwi_i[it] = wwi_i[q];  Rwwi_g[it] = wwi_g[q];
    }
  }

  const float b_i  = bias_b[J], b_o = bias_b[Hq + J], b_g = bias_b[2*Hq + J];
  const float ab_J = bias_ab[J];
  const float wb_f = bias_wb[J], wb_i = bias_wb[Hq + J], wb_g = bias_wb[2*Hq + J];

  float* out_h = out + (size_t)seq * Tq * Hq;            // hs block
  float* out_c = out + ((size_t)Bq + seq) * Tq * Hq;     // cs block

  __shared__ __align__(16) float sh_h[Hq];    // persistent: holds h_{t-1} at phase A
  __shared__ __align__(16) float sh_p0[Hq];
  __shared__ __align__(16) float sh_p1[Hq];
  __shared__ __align__(16) float sh_x[DCq];
  __shared__ __align__(16) float sh_xw0[DCq];
  __shared__ __align__(16) float sh_xw1[DCq];

  for (int t = 0; t < Tq; ++t){
    // ---- phase A staging: poll pend; prefetch x and sense rows for phase B ----
    if (t == 0){
      sh_h[i0] = 0.f; sh_h[i1] = 0.f;
      sh_p0[i0] = 0.f; sh_p0[i1] = 0.f;
      sh_p1[i0] = 0.f; sh_p1[i1] = 0.f;
    } else {
      const u64* p0 = pnd + ((size_t)(t & 3) * 2 + 0) * Hq;
      sh_p0[i0] = spin64(p0 + i0, (unsigned)t);
      sh_p0[i1] = spin64(p0 + i1, (unsigned)t);
      if (t >= 3){
        const u64* p1 = pnd + ((size_t)(t & 3) * 2 + 1) * Hq;
        sh_p1[i0] = spin64(p1 + i0, (unsigned)(t - 2));
        sh_p1[i1] = spin64(p1 + i1, (unsigned)(t - 2));
      } else {
        sh_p1[i0] = 0.f; sh_p1[i1] = 0.f;
      }
    }
    if (tid < DCq){
      sh_x[tid] = char_emb[((size_t)seq * Tq + t) * DCq + tid];
    } else {
      const int k = tid - DCq;
      const int w0 = word_ids[((size_t)seq * Tq + t) * 2 + 0];
      const int w1 = word_ids[((size_t)seq * Tq + t) * 2 + 1];
      sh_xw0[k] = sense_table[(size_t)w0 * DCq + k];
      sh_xw1[k] = sense_table[(size_t)w1 * DCq + k];
    }
    __syncthreads();

    // ---- char-cell dots ----
    float a_i = 0.f, a_o = 0.f, a_g = 0.f, a_p0 = 0.f, a_p1 = 0.f, a_xa = 0.f;
#pragma unroll
    for (int it = 0; it < 8; ++it){
      const int k0 = it * 64 + lane * 4;   // 2-way LDS aliasing (free)
      float4 hv  = *(const float4*)(sh_h  + k0);
      float4 p0v = *(const float4*)(sh_p0 + k0);
      float4 p1v = *(const float4*)(sh_p1 + k0);
      fma4(a_i, Rwhh_i[it], hv);
      fma4(a_o, Rwhh_o[it], hv);
      fma4(a_g, Rwhh_g[it], hv);
      fma4(a_p0, Rawhh[it], p0v);
      fma4(a_p1, Rawhh[it], p1v);
    }
#pragma unroll
    for (int it = 0; it < 2; ++it){
      const int k0 = it * 64 + lane * 4;
      float4 xv = *(const float4*)(sh_x + k0);
      fma4(a_i,  Rwih_i[it], xv);
      fma4(a_o,  Rwih_o[it], xv);
      fma4(a_g,  Rwih_g[it], xv);
      fma4(a_xa, Rawih[it],  xv);
    }
    a_i  = red16(a_i);  a_o  = red16(a_o);  a_g  = red16(a_g);
    a_p0 = red16(a_p0); a_p1 = red16(a_p1); a_xa = red16(a_xa);

    const float gi = sigm(a_i + b_i);
    const float go = sigm(a_o + b_o);
    const float gg = tanhf(a_g + b_g);
    float c1;
    if (t == 0){
      c1 = gi * gg;                       // c_plain with c=0
    } else {
      const float base = a_xa + ab_J;
      const float ea0 = __expf(sigm(base + a_p0));   // m0 = 1 for t>=1
      const float ei  = __expf(gi);
      float num = ei * gg + ea0 * sh_p0[J];
      float den = ei + ea0;
      if (t >= 3){                                    // m1 = 1 for t>=3
        const float ea1 = __expf(sigm(base + a_p1));
        num += ea1 * sh_p1[J];
        den += ea1;
      }
      c1 = num / den;
    }
    const float h1 = go * tanhf(c1);
    if (lane == 0){
      pub64(hpub + (size_t)(t & 1) * Hq + J, h1, (unsigned)(t + 1));  // one 8B store: value+gen
      out_h[(size_t)t * Hq + J] = h1;   // harness-only: plain stores
      out_c[(size_t)t * Hq + J] = c1;
    }
    __syncthreads();   // char compute done reading sh_h -> safe to overwrite

    // ---- phase B staging: poll full h1 into persistent sh_h ----
    {
      const u64* hp = hpub + (size_t)(t & 1) * Hq;
      sh_h[i0] = spin64(hp + i0, (unsigned)(t + 1));
      sh_h[i1] = spin64(hp + i1, (unsigned)(t + 1));
    }
    __syncthreads();

    // ---- word-cell ----
    float r_f = 0.f, r_i = 0.f, r_g = 0.f;
    float x_f0 = 0.f, x_i0 = 0.f, x_g0 = 0.f, x_f1 = 0.f, x_i1 = 0.f, x_g1 = 0.f;
#pragma unroll
    for (int it = 0; it < 8; ++it){
      const int k0 = it * 64 + lane * 4;
      float4 hv = *(const float4*)(sh_h + k0);
      fma4(r_f, Rwwh_f[it], hv);
      fma4(r_i, Rwwh_i[it], hv);
      fma4(r_g, Rwwh_g[it], hv);
    }
#pragma unroll
    for (int it = 0; it < 2; ++it){
      const int k0 = it * 64 + lane * 4;
      float4 x0 = *(const float4*)(sh_xw0 + k0);
      float4 x1 = *(const float4*)(sh_xw1 + k0);
      fma4(x_f0, Rwwi_f[it], x0);  fma4(x_f1, Rwwi_f[it], x1);
      fma4(x_i0, Rwwi_i[it], x0);  fma4(x_i1, Rwwi_i[it], x1);
      fma4(x_g0, Rwwi_g[it], x0);  fma4(x_g1, Rwwi_g[it], x1);
    }
    r_f  = red16(r_f);  r_i  = red16(r_i);  r_g  = red16(r_g);
    x_f0 = red16(x_f0); x_i0 = red16(x_i0); x_g0 = red16(x_g0);
    x_f1 = red16(x_f1); x_i1 = red16(x_i1); x_g1 = red16(x_g1);

    if (lane == 0){
      const float f0  = sigm(r_f + x_f0 + wb_f);
      const float iw0 = sigm(r_i + x_i0 + wb_i);
      const float g0  = tanhf(r_g + x_g0 + wb_g);
      const float cw0 = f0 * c1 + iw0 * g0;
      const float f1  = sigm(r_f + x_f1 + wb_f);
      const float iw1 = sigm(r_i + x_i1 + wb_i);
      const float g1  = tanhf(r_g + x_g1 + wb_g);
      const float cw1 = f1 * c1 + iw1 * g1;
      // gen = production step + 1; consumers poll: p0>=t_c, p1>=t_c-2
      pub64(pnd + ((size_t)((t + 1) & 3) * 2 + 0) * Hq + J, cw0, (unsigned)(t + 1));
      pub64(pnd + ((size_t)((t + 3) & 3) * 2 + 1) * Hq + J, cw1, (unsigned)(t + 1));
    }
    __syncthreads();   // word compute done reading sh_xw* -> next phase A may restage
  }
}

extern "C" void kernel_launch(void* const* d_in, const int* in_sizes, int n_in,
                              void* d_out, int out_size, void* d_ws, size_t ws_size,
                              hipStream_t stream){
  const float* char_emb = (const float*)d_in[0];
  const int*   word_ids = (const int*)d_in[1];
  const float* sense    = (const float*)d_in[2];
  const float* w_ih     = (const float*)d_in[3];
  const float* w_hh     = (const float*)d_in[4];
  const float* bb       = (const float*)d_in[5];
  const float* aw_ih    = (const float*)d_in[6];
  const float* aw_hh    = (const float*)d_in[7];
  const float* ab       = (const float*)d_in[8];
  const float* ww_ih    = (const float*)d_in[9];
  const float* ww_hh    = (const float*)d_in[10];
  const float* wb       = (const float*)d_in[11];
  unsigned char* ws = (unsigned char*)d_ws;
  float* out = (float*)d_out;

  // zero all generation words (h_pub + pend) — ws is re-poisoned before every launch
  hipMemsetAsync(ws, 0, WIHT_OFF, stream);

  // one-time (per launch) weight convert+transpose to bf16
  transpose_bf16<<<512, NTHR, 0, stream>>>(w_ih,  (__hip_bfloat16*)(ws + WIHT_OFF),  7, 128*1536, 1536);
  transpose_bf16<<<512, NTHR, 0, stream>>>(w_hh,  (__hip_bfloat16*)(ws + WHHT_OFF),  9, 512*1536, 1536);
  transpose_bf16<<<512, NTHR, 0, stream>>>(aw_ih, (__hip_bfloat16*)(ws + AWIHT_OFF), 7, 128*512,  512);
  transpose_bf16<<<512, NTHR, 0, stream>>>(aw_hh, (__hip_bfloat16*)(ws + AWHHT_OFF), 9, 512*512,  512);
  transpose_bf16<<<512, NTHR, 0, stream>>>(ww_ih, (__hip_bfloat16*)(ws + WWIHT_OFF), 7, 128*1536, 1536);
  transpose_bf16<<<512, NTHR, 0, stream>>>(ww_hh, (__hip_bfloat16*)(ws + WWHHT_OFF), 9, 512*1536, 1536);

  dim3 grid(Bq, NWG);   // x = seq (XCD-local heuristic), y = wg slice; 256 WGs co-resident
  lattice_main<<<grid, NTHR, 0, stream>>>(char_emb, word_ids, sense, bb, ab, wb, ws, out);
}

// Round 5
// 5606.942 us; speedup vs baseline: 4.0410x; 1.3055x over previous
//
#include <hip/hip_runtime.h>
#include <hip/hip_bf16.h>

// LatticeLSTM on MI355X — Round 5: single-exposed-round-trip dataflow.
// Step layout (2 syncthreads/step, parity-double-buffered LDS):
//   A1: i/o/g/xa matvecs over h(t-1),x(t)   [pend NOT needed]
//   A2: poll pend for step t (published last step -> usually visible)
//   S1
//   A3: alpha matvecs + gates -> c1,h1; publish {h1,gen} (8B atomic)
//   B2: stage x/xw(t+1) (overlaps) + poll full h(t)  <-- the ONE exposed trip
//   S2
//   B3: word gates -> cw0,cw1; publish pend {val,gen}
// All spin loops issue their 2-4 loads independently (one round trip, not
// serialized) and have NO s_sleep: the ~700cyc dependent-load latency is the
// backoff; addresses are distributed (no hot line).
// pmask is data-independent: m0=(t>=1), m1=(t>=3); c_plain only at t=0.
// Progress needs all 256 WGs co-resident (1 WG/CU; LDS ~11KB, VGPR<256).

#define Bq 8
#define Tq 1024
#define DCq 128
#define Hq 512
#define NWG 32
#define NTHR 256

typedef unsigned long long u64;

// ws byte offsets
#define HPUB_OFF  0u         // u64 h_pub[8][2][512]     = 65536
#define PENDP_OFF 65536u     // u64 pend[8][4][2][512]   = 262144
#define WIHT_OFF  327680u    // bf16 [1536][128]
#define WHHT_OFF  720896u    // bf16 [1536][512]
#define AWIHT_OFF 2293760u   // bf16 [512][128]
#define AWHHT_OFF 2424832u   // bf16 [512][512]
#define WWIHT_OFF 2949120u   // bf16 [1536][128]
#define WWHHT_OFF 3342336u   // bf16 [1536][512]  (end 4915200)

__device__ __forceinline__ float bflo(unsigned u){ return __uint_as_float(u << 16); }
__device__ __forceinline__ float bfhi(unsigned u){ return __uint_as_float(u & 0xffff0000u); }
__device__ __forceinline__ float sigm(float x){ return 1.0f / (1.0f + __expf(-x)); }

__device__ __forceinline__ void fma4(float& acc, uint2 w, float4 v){
  acc = fmaf(bflo(w.x), v.x, acc);
  acc = fmaf(bfhi(w.x), v.y, acc);
  acc = fmaf(bflo(w.y), v.z, acc);
  acc = fmaf(bfhi(w.y), v.w, acc);
}

__device__ __forceinline__ float red16(float x){
  x += __shfl_xor(x, 8, 16);
  x += __shfl_xor(x, 4, 16);
  x += __shfl_xor(x, 2, 16);
  x += __shfl_xor(x, 1, 16);
  return x;
}

__device__ __forceinline__ u64 pack64(float v, unsigned gen){
  return ((u64)gen << 32) | (u64)__float_as_uint(v);
}
__device__ __forceinline__ void pub64(u64* p, float v, unsigned gen){
  __hip_atomic_store(p, pack64(v, gen), __ATOMIC_RELAXED, __HIP_MEMORY_SCOPE_AGENT);
}
__device__ __forceinline__ u64 ld64(const u64* p){
  return __hip_atomic_load(p, __ATOMIC_RELAXED, __HIP_MEMORY_SCOPE_AGENT);
}
__device__ __forceinline__ unsigned genof(u64 v){ return (unsigned)(v >> 32); }
__device__ __forceinline__ float valof(u64 v){ return __uint_as_float((unsigned)v); }

// src [K][N] fp32 -> dst [N][K] bf16 (transpose + convert). K is pow2.
__global__ void transpose_bf16(const float* __restrict__ src, __hip_bfloat16* __restrict__ dst,
                               int kshift, int total, int N){
  const int K = 1 << kshift;
  for (int idx = blockIdx.x * blockDim.x + threadIdx.x; idx < total;
       idx += gridDim.x * blockDim.x){
    int n = idx >> kshift;
    int k = idx & (K - 1);
    dst[idx] = __float2bfloat16(src[(size_t)k * N + n]);
  }
}

__global__ void __launch_bounds__(NTHR, 1)
lattice_main(const float* __restrict__ char_emb,
             const int*   __restrict__ word_ids,
             const float* __restrict__ sense_table,
             const float* __restrict__ bias_b,
             const float* __restrict__ bias_ab,
             const float* __restrict__ bias_wb,
             unsigned char* __restrict__ ws,
             float* __restrict__ out)
{
  const int seq  = blockIdx.x;
  const int wg   = blockIdx.y;
  const int tid  = threadIdx.x;
  const int grp  = tid >> 4;
  const int lane = tid & 15;
  const int J    = wg * 16 + grp;               // owned H column
  const int i0   = tid * 2, i1 = tid * 2 + 1;   // poll columns for this thread

  u64* hpub = (u64*)(ws + HPUB_OFF)  + (size_t)seq * 2 * Hq;      // [parity][col]
  u64* pnd  = (u64*)(ws + PENDP_OFF) + (size_t)seq * 4 * 2 * Hq;  // [slot][k][col]

  const uint2* w_ihT  = (const uint2*)(ws + WIHT_OFF);
  const uint2* w_hhT  = (const uint2*)(ws + WHHT_OFF);
  const uint2* aw_ihT = (const uint2*)(ws + AWIHT_OFF);
  const uint2* aw_hhT = (const uint2*)(ws + AWHHT_OFF);
  const uint2* ww_ihT = (const uint2*)(ws + WWIHT_OFF);
  const uint2* ww_hhT = (const uint2*)(ws + WWHHT_OFF);

  // ---- hoist ALL weights into registers (addresses are t-invariant) ----
  uint2 Rwhh_i[8], Rwhh_o[8], Rwhh_g[8], Rawhh[8];
  uint2 Rwwh_f[8], Rwwh_i[8], Rwwh_g[8];
  uint2 Rwih_i[2], Rwih_o[2], Rwih_g[2], Rawih[2];
  uint2 Rwwi_f[2], Rwwi_i[2], Rwwi_g[2];
  {
    const uint2* whh_i = w_hhT  + (size_t)(0*Hq + J) * 128;
    const uint2* whh_o = w_hhT  + (size_t)(1*Hq + J) * 128;
    const uint2* whh_g = w_hhT  + (size_t)(2*Hq + J) * 128;
    const uint2* awhh  = aw_hhT + (size_t)J * 128;
    const uint2* wwh_f = ww_hhT + (size_t)(0*Hq + J) * 128;
    const uint2* wwh_i = ww_hhT + (size_t)(1*Hq + J) * 128;
    const uint2* wwh_g = ww_hhT + (size_t)(2*Hq + J) * 128;
#pragma unroll
    for (int it = 0; it < 8; ++it){
      const int q = it * 16 + lane;
      Rwhh_i[it] = whh_i[q];  Rwhh_o[it] = whh_o[q];  Rwhh_g[it] = whh_g[q];
      Rawhh[it]  = awhh[q];
      Rwwh_f[it] = wwh_f[q];  Rwwh_i[it] = wwh_i[q];  Rwwh_g[it] = wwh_g[q];
    }
    const uint2* wih_i = w_ihT  + (size_t)(0*Hq + J) * 32;
    const uint2* wih_o = w_ihT  + (size_t)(1*Hq + J) * 32;
    const uint2* wih_g = w_ihT  + (size_t)(2*Hq + J) * 32;
    const uint2* awih  = aw_ihT + (size_t)J * 32;
    const uint2* wwi_f = ww_ihT + (size_t)(0*Hq + J) * 32;
    const uint2* wwi_i = ww_ihT + (size_t)(1*Hq + J) * 32;
    const uint2* wwi_g = ww_ihT + (size_t)(2*Hq + J) * 32;
#pragma unroll
    for (int it = 0; it < 2; ++it){
      const int q = it * 16 + lane;
      Rwih_i[it] = wih_i[q];  Rwih_o[it] = wih_o[q];  Rwih_g[it] = wih_g[q];
      Rawih[it]  = awih[q];
      Rwwi_f[it] = wwi_f[q];  Rwwi_i[it] = wwi_i[q];  Rwwi_g[it] = wwi_g[q];
    }
  }

  const float b_i  = bias_b[J], b_o = bias_b[Hq + J], b_g = bias_b[2*Hq + J];
  const float ab_J = bias_ab[J];
  const float wb_f = bias_wb[J], wb_i = bias_wb[Hq + J], wb_g = bias_wb[2*Hq + J];

  float* out_h = out + (size_t)seq * Tq * Hq;            // hs block
  float* out_c = out + ((size_t)Bq + seq) * Tq * Hq;     // cs block

  __shared__ __align__(16) float shH[2][Hq];      // h by parity: shH[t&1] = h(t)
  __shared__ __align__(16) float sh_p0[Hq];
  __shared__ __align__(16) float sh_p1[Hq];
  __shared__ __align__(16) float shx[2][DCq];     // x(t) in shx[t&1]
  __shared__ __align__(16) float shxw0[2][DCq];   // xw(t) in shxw*[t&1]
  __shared__ __align__(16) float shxw1[2][DCq];

  // ---- pre-loop staging: zeros + x(0), xw(0) ----
  shH[0][i0] = 0.f; shH[0][i1] = 0.f;
  shH[1][i0] = 0.f; shH[1][i1] = 0.f;
  sh_p0[i0] = 0.f; sh_p0[i1] = 0.f;
  sh_p1[i0] = 0.f; sh_p1[i1] = 0.f;
  if (tid < DCq){
    shx[0][tid] = char_emb[((size_t)seq * Tq + 0) * DCq + tid];
  } else {
    const int k = tid - DCq;
    const int w0 = word_ids[(size_t)seq * Tq * 2 + 0];
    const int w1 = word_ids[(size_t)seq * Tq * 2 + 1];
    shxw0[0][k] = sense_table[(size_t)w0 * DCq + k];
    shxw1[0][k] = sense_table[(size_t)w1 * DCq + k];
  }
  __syncthreads();

  for (int t = 0; t < Tq; ++t){
    const int par = t & 1;
    const float* hprev = shH[par ^ 1];     // h(t-1)

    // ---- A1: i/o/g/xa matvecs (pend NOT needed) ----
    float a_i = 0.f, a_o = 0.f, a_g = 0.f, a_xa = 0.f;
#pragma unroll
    for (int it = 0; it < 8; ++it){
      const int k0 = it * 64 + lane * 4;
      float4 hv = *(const float4*)(hprev + k0);
      fma4(a_i, Rwhh_i[it], hv);
      fma4(a_o, Rwhh_o[it], hv);
      fma4(a_g, Rwhh_g[it], hv);
    }
#pragma unroll
    for (int it = 0; it < 2; ++it){
      const int k0 = it * 64 + lane * 4;
      float4 xv = *(const float4*)(shx[par] + k0);
      fma4(a_i,  Rwih_i[it], xv);
      fma4(a_o,  Rwih_o[it], xv);
      fma4(a_g,  Rwih_g[it], xv);
      fma4(a_xa, Rawih[it],  xv);
    }

    // ---- A2: poll pend for step t (usually already visible) ----
    if (t >= 3){
      const u64* p0 = pnd + ((size_t)(t & 3) * 2 + 0) * Hq;
      const u64* p1 = pnd + ((size_t)(t & 3) * 2 + 1) * Hq;
      const unsigned tg0 = (unsigned)t, tg1 = (unsigned)(t - 2);
      u64 a, b, c, d;
      for (;;){
        a = ld64(p0 + i0); b = ld64(p0 + i1);
        c = ld64(p1 + i0); d = ld64(p1 + i1);
        if (genof(a) >= tg0 && genof(b) >= tg0 &&
            genof(c) >= tg1 && genof(d) >= tg1) break;
      }
      sh_p0[i0] = valof(a); sh_p0[i1] = valof(b);
      sh_p1[i0] = valof(c); sh_p1[i1] = valof(d);
    } else if (t >= 1){
      const u64* p0 = pnd + ((size_t)(t & 3) * 2 + 0) * Hq;
      const unsigned tg0 = (unsigned)t;
      u64 a, b;
      for (;;){
        a = ld64(p0 + i0); b = ld64(p0 + i1);
        if (genof(a) >= tg0 && genof(b) >= tg0) break;
      }
      sh_p0[i0] = valof(a); sh_p0[i1] = valof(b);
      // sh_p1 stays zero (mask m1=0 for t<3)
    }
    __syncthreads();   // S1

    // ---- A3: alpha matvecs + gates ----
    float a_p0 = 0.f, a_p1 = 0.f;
#pragma unroll
    for (int it = 0; it < 8; ++it){
      const int k0 = it * 64 + lane * 4;
      float4 p0v = *(const float4*)(sh_p0 + k0);
      float4 p1v = *(const float4*)(sh_p1 + k0);
      fma4(a_p0, Rawhh[it], p0v);
      fma4(a_p1, Rawhh[it], p1v);
    }
    a_i  = red16(a_i);  a_o  = red16(a_o);  a_g  = red16(a_g);
    a_xa = red16(a_xa); a_p0 = red16(a_p0); a_p1 = red16(a_p1);

    const float gi = sigm(a_i + b_i);
    const float go = sigm(a_o + b_o);
    const float gg = tanhf(a_g + b_g);
    float c1;
    if (t == 0){
      c1 = gi * gg;                       // c_plain with c=0
    } else {
      const float base = a_xa + ab_J;
      const float ea0 = __expf(sigm(base + a_p0));   // m0=1 for t>=1
      const float ei  = __expf(gi);
      float num = ei * gg + ea0 * sh_p0[J];
      float den = ei + ea0;
      if (t >= 3){                                    // m1=1 for t>=3
        const float ea1 = __expf(sigm(base + a_p1));
        num += ea1 * sh_p1[J];
        den += ea1;
      }
      c1 = num / den;
    }
    const float h1 = go * tanhf(c1);
    if (lane == 0){
      pub64(hpub + (size_t)par * Hq + J, h1, (unsigned)(t + 1));  // value+gen, one 8B store
      out_h[(size_t)t * Hq + J] = h1;
      out_c[(size_t)t * Hq + J] = c1;
    }

    // ---- B2: stage x/xw(t+1) (overlaps poll) + poll full h(t) ----
    {
      const int tn = (t + 1 < Tq) ? t + 1 : t;
      if (tid < DCq){
        shx[par ^ 1][tid] = char_emb[((size_t)seq * Tq + tn) * DCq + tid];
      } else {
        const int k = tid - DCq;
        const int w0 = word_ids[((size_t)seq * Tq + tn) * 2 + 0];
        const int w1 = word_ids[((size_t)seq * Tq + tn) * 2 + 1];
        shxw0[par ^ 1][k] = sense_table[(size_t)w0 * DCq + k];
        shxw1[par ^ 1][k] = sense_table[(size_t)w1 * DCq + k];
      }
      const u64* hp = hpub + (size_t)par * Hq;
      const unsigned tg = (unsigned)(t + 1);
      u64 a, b;
      for (;;){
        a = ld64(hp + i0); b = ld64(hp + i1);
        if (genof(a) >= tg && genof(b) >= tg) break;
      }
      shH[par][i0] = valof(a); shH[par][i1] = valof(b);
    }
    __syncthreads();   // S2

    // ---- B3: word gates ----
    float r_f = 0.f, r_i = 0.f, r_g = 0.f;
    float x_f0 = 0.f, x_i0 = 0.f, x_g0 = 0.f, x_f1 = 0.f, x_i1 = 0.f, x_g1 = 0.f;
#pragma unroll
    for (int it = 0; it < 8; ++it){
      const int k0 = it * 64 + lane * 4;
      float4 hv = *(const float4*)(shH[par] + k0);
      fma4(r_f, Rwwh_f[it], hv);
      fma4(r_i, Rwwh_i[it], hv);
      fma4(r_g, Rwwh_g[it], hv);
    }
#pragma unroll
    for (int it = 0; it < 2; ++it){
      const int k0 = it * 64 + lane * 4;
      float4 x0 = *(const float4*)(shxw0[par] + k0);
      float4 x1 = *(const float4*)(shxw1[par] + k0);
      fma4(x_f0, Rwwi_f[it], x0);  fma4(x_f1, Rwwi_f[it], x1);
      fma4(x_i0, Rwwi_i[it], x0);  fma4(x_i1, Rwwi_i[it], x1);
      fma4(x_g0, Rwwi_g[it], x0);  fma4(x_g1, Rwwi_g[it], x1);
    }
    r_f  = red16(r_f);  r_i  = red16(r_i);  r_g  = red16(r_g);
    x_f0 = red16(x_f0); x_i0 = red16(x_i0); x_g0 = red16(x_g0);
    x_f1 = red16(x_f1); x_i1 = red16(x_i1); x_g1 = red16(x_g1);

    if (lane == 0){
      const float f0  = sigm(r_f + x_f0 + wb_f);
      const float iw0 = sigm(r_i + x_i0 + wb_i);
      const float g0  = tanhf(r_g + x_g0 + wb_g);
      const float cw0 = f0 * c1 + iw0 * g0;
      const float f1  = sigm(r_f + x_f1 + wb_f);
      const float iw1 = sigm(r_i + x_i1 + wb_i);
      const float g1  = tanhf(r_g + x_g1 + wb_g);
      const float cw1 = f1 * c1 + iw1 * g1;
      // gen = production step + 1; consumers poll p0>=t_c, p1>=t_c-2
      pub64(pnd + ((size_t)((t + 1) & 3) * 2 + 0) * Hq + J, cw0, (unsigned)(t + 1));
      pub64(pnd + ((size_t)((t + 3) & 3) * 2 + 1) * Hq + J, cw1, (unsigned)(t + 1));
    }
    // no barrier here: next A1 touches only shH[par^1]/shx[par^1] (disjoint),
    // next A2 LDS writes are fenced by S1; pend LDS buffers re-written only
    // after S2 of this step (cross-thread ordering via S1/S2 chain).
  }
}

extern "C" void kernel_launch(void* const* d_in, const int* in_sizes, int n_in,
                              void* d_out, int out_size, void* d_ws, size_t ws_size,
                              hipStream_t stream){
  const float* char_emb = (const float*)d_in[0];
  const int*   word_ids = (const int*)d_in[1];
  const float* sense    = (const float*)d_in[2];
  const float* w_ih     = (const float*)d_in[3];
  const float* w_hh     = (const float*)d_in[4];
  const float* bb       = (const float*)d_in[5];
  const float* aw_ih    = (const float*)d_in[6];
  const float* aw_hh    = (const float*)d_in[7];
  const float* ab       = (const float*)d_in[8];
  const float* ww_ih    = (const float*)d_in[9];
  const float* ww_hh    = (const float*)d_in[10];
  const float* wb       = (const float*)d_in[11];
  unsigned char* ws = (unsigned char*)d_ws;
  float* out = (float*)d_out;

  // zero all generation words (h_pub + pend) — ws is re-poisoned before every launch
  hipMemsetAsync(ws, 0, WIHT_OFF, stream);

  // one-time (per launch) weight convert+transpose to bf16
  transpose_bf16<<<512, NTHR, 0, stream>>>(w_ih,  (__hip_bfloat16*)(ws + WIHT_OFF),  7, 128*1536, 1536);
  transpose_bf16<<<512, NTHR, 0, stream>>>(w_hh,  (__hip_bfloat16*)(ws + WHHT_OFF),  9, 512*1536, 1536);
  transpose_bf16<<<512, NTHR, 0, stream>>>(aw_ih, (__hip_bfloat16*)(ws + AWIHT_OFF), 7, 128*512,  512);
  transpose_bf16<<<512, NTHR, 0, stream>>>(aw_hh, (__hip_bfloat16*)(ws + AWHHT_OFF), 9, 512*512,  512);
  transpose_bf16<<<512, NTHR, 0, stream>>>(ww_ih, (__hip_bfloat16*)(ws + WWIHT_OFF), 7, 128*1536, 1536);
  transpose_bf16<<<512, NTHR, 0, stream>>>(ww_hh, (__hip_bfloat16*)(ws + WWHHT_OFF), 9, 512*1536, 1536);

  dim3 grid(Bq, NWG);   // x = seq (XCD-local heuristic), y = wg slice
  lattice_main<<<grid, NTHR, 0, stream>>>(char_emb, word_ids, sense, bb, ab, wb, ws, out);
}